// Round 1
// baseline (624.575 us; speedup 1.0000x reference)
//
#include <hip/hip_runtime.h>
#include <math.h>

// Problem constants
#define TT 32
#define BB 128
#define DD 256
#define HH 768
#define MAXP 8

// Decomposition: 8 rowgroups (16 rows) x 12 col-blocks (64 cols), 256 thr (4 waves = 4 col-tiles)
#define RG   8
#define RPG  16
#define CB   12
#define CS   64
#define NTH  256
#define NCH  24    // K chunks of 32

#define OFF_LAST  ((size_t)TT * BB * HH)
#define OFF_PCOST (OFF_LAST + (size_t)BB * HH)
#define OFF_STEPS (OFF_PCOST + BB)

#define ASCOPE __HIP_MEMORY_SCOPE_AGENT

typedef __attribute__((ext_vector_type(8))) short s16x8;
typedef __attribute__((ext_vector_type(4))) float f32x4;
typedef unsigned long long ull;

static __device__ __forceinline__ unsigned short f2bf(float f) {
    unsigned u = __float_as_uint(f);
    u = (u + 0x7fffu + ((u >> 16) & 1u)) >> 16;   // RNE
    return (unsigned short)u;
}
static __device__ __forceinline__ float bf2f(unsigned short h) {
    return __uint_as_float(((unsigned)h) << 16);
}
// bf16-target precision is 2^-9; __expf error ~1e-6 is invisible. Handles +-inf limits.
static __device__ __forceinline__ float fast_tanh(float v) {
    return 1.f - 2.f / (__expf(2.f * v) + 1.f);
}

union AU { float4 f; s16x8 s; unsigned short e[8]; };

__launch_bounds__(NTH, 1)
__global__ void act_kernel(const float* __restrict__ x,
                           const float* __restrict__ Wih,
                           const float* __restrict__ Whh,
                           const float* __restrict__ bih,
                           const float* __restrict__ bhh,
                           const float* __restrict__ wpv,
                           const float* __restrict__ bp,
                           float* __restrict__ out,
                           unsigned* __restrict__ flags,
                           s16x8* __restrict__ hxe,
                           float* __restrict__ zpt)
{
    const int tid  = threadIdx.x;
    const int rg   = blockIdx.x & 7;     // rowgroup -> XCD (perf heuristic only)
    const int cbk  = blockIdx.x >> 3;    // col-block [0,12)
    const int r0   = rg * RPG;
    const int c0   = cbk * CS;
    const int CT   = tid >> 6;           // wave = col-tile [0,4)
    const int lane = tid & 63;
    const int am   = lane & 15;          // A-frag row / C-frag col
    const int aq   = lane >> 4;

    // LDS ~68 KB
    __shared__ s16x8 A_s[NCH * 64];        // hx(t, k=0) A-frags (written at finalize)
    __shared__ s16x8 WB_s[4 * 8 * 64];     // Wih B-frags (32 KB)
    __shared__ s16x8 xA_s[8 * 64];         // x_t A-frags (8 KB)
    __shared__ unsigned short hxn_s[RPG][72];   // new hx slice, bf16 (pad 72)
    __shared__ float wp_s[CS];

    // ---- init: Whh B-frags -> permanent VGPRs (96) ----
    s16x8 Breg[NCH];
    {
        const float* wr = Whh + (size_t)(c0 + CT*16 + am) * HH + aq*8;
        for (int ch = 0; ch < NCH; ++ch) {
            float4 a0 = *(const float4*)(wr + ch*32);
            float4 a1 = *(const float4*)(wr + ch*32 + 4);
            union { s16x8 v; unsigned short e[8]; } u;
            u.e[0]=f2bf(a0.x); u.e[1]=f2bf(a0.y); u.e[2]=f2bf(a0.z); u.e[3]=f2bf(a0.w);
            u.e[4]=f2bf(a1.x); u.e[5]=f2bf(a1.y); u.e[6]=f2bf(a1.z); u.e[7]=f2bf(a1.w);
            Breg[ch] = u.v;
        }
    }
    // Wih B-frags -> LDS (row stride 257 unaligned: scalar loads, init-only)
    for (int ch = 0; ch < 8; ++ch) {
        const float* wr = Wih + (size_t)(c0 + CT*16 + am) * (DD+1) + ch*32 + aq*8;
        union { s16x8 v; unsigned short e[8]; } u;
        #pragma unroll
        for (int j = 0; j < 8; ++j) u.e[j] = f2bf(wr[j]);
        WB_s[(CT*8 + ch)*64 + lane] = u.v;
    }
    if (tid < CS) wp_s[tid] = wpv[c0 + tid];
    // per-lane column constants (col = c0 + CT*16 + am)
    const int myc = c0 + CT*16 + am;
    const float bs_lane = bih[myc] + bhh[myc];
    const float wfl     = Wih[(size_t)myc*(DD+1) + DD];   // ponder-flag column
    const float bp0     = bp[0];
    {
        s16x8 z8 = {0,0,0,0,0,0,0,0};
        #pragma unroll
        for (int j = 0; j < 6; ++j) A_s[j*NTH + tid] = z8;   // hx0 = 0
    }

    float pc = 0.f;     // per-lane pcost for row am
    unsigned it = 0;    // monotone publish counter (= flag value - 1 of last publish)

    // Publish round `it`: wave 0 repacks hxn_s into A-frag layout and pushes it + the
    // 16 z-row partials; release fence drains ONLY its own stores, then flag.
    // Waves 1-3 never touch global here: their next spin on the OWN flag doubles as
    // the "publish done / hxn_s free" intra-block sync.
    auto do_publish = [&]() {
        const unsigned par = it & 1u;
        s16x8* exw = hxe + (size_t)(rg*2 + par) * (NCH*64);
        float* zpw = zpt + (size_t)(rg*2 + par) * (RPG*CB);
        if (CT == 0) {
            // hx slice (2 chunks, A-frag layout; 16B-aligned LDS reads)
            exw[(2*cbk)*64   + lane] = *(const s16x8*)&hxn_s[am][aq*8];
            exw[(2*cbk+1)*64 + lane] = *(const s16x8*)&hxn_s[am][32 + aq*8];
            // z partials: lane -> (row zr, 16-col group zc); pair-tree over zc
            const int zr = lane >> 2, zc = lane & 3;
            float sz = 0.f;
            #pragma unroll
            for (int i = 0; i < 16; ++i)
                sz += bf2f(hxn_s[zr][zc*16 + i]) * wp_s[zc*16 + i];
            sz += __shfl_xor(sz, 1);
            sz += __shfl_xor(sz, 2);
            if (zc == 0) zpw[zr*CB + cbk] = sz;
            __builtin_amdgcn_fence(__ATOMIC_RELEASE, "agent");
            if (lane == 0)
                __hip_atomic_store(&flags[rg*16 + cbk], it + 1u, __ATOMIC_RELAXED, ASCOPE);
        }
        ++it;
    };

    for (int t = 0; t < TT; ++t) {
        // ---- stage x_t slice as bf16 A-frags ----
        #pragma unroll
        for (int j = 0; j < 2; ++j) {
            const int s = j*NTH + tid;       // ch = s>>6, lane = s&63 == lane
            const int ch = s >> 6;
            const float* xb = x + ((size_t)t*BB + r0 + am)*DD + ch*32 + aq*8;
            float4 a0 = *(const float4*)xb;
            float4 a1 = *(const float4*)(xb + 4);
            union { s16x8 v; unsigned short e[8]; } u;
            u.e[0]=f2bf(a0.x); u.e[1]=f2bf(a0.y); u.e[2]=f2bf(a0.z); u.e[3]=f2bf(a0.w);
            u.e[4]=f2bf(a1.x); u.e[5]=f2bf(a1.y); u.e[6]=f2bf(a1.z); u.e[7]=f2bf(a1.w);
            xA_s[s] = u.v;
        }
        __syncthreads();   // T0: guards A_s (init/finalize) + xA_s writes

        // ---- xi tile per wave: x @ Wih^T + bias (MFMA, registers) ----
        f32x4 xi;
        {
            f32x4 a = {0.f,0.f,0.f,0.f};
            #pragma unroll
            for (int ch = 0; ch < 8; ++ch)
                a = __builtin_amdgcn_mfma_f32_16x16x32_bf16(
                        xA_s[ch*64 + lane], WB_s[(CT*8 + ch)*64 + lane], a, 0, 0, 0);
            xi[0]=a[0]+bs_lane; xi[1]=a[1]+bs_lane; xi[2]=a[2]+bs_lane; xi[3]=a[3]+bs_lane;
        }

        // per-lane replicated row state (row = am; 16 replicas compute identically)
        float ahx[48];
        #pragma unroll
        for (int q = 0; q < 48; ++q) ahx[q] = 0.f;
        float ah = 0.f, sc = 0.f, spc = 0.f;
        int act = 1;

        // ---- k=0 matvec from LDS A_s (hx carried from finalize; flag col = 0) ----
        {
            f32x4 acc = xi;
            #pragma unroll
            for (int ch = 0; ch < NCH; ++ch)
                acc = __builtin_amdgcn_mfma_f32_16x16x32_bf16(
                        A_s[ch*64 + lane], Breg[ch], acc, 0, 0, 0);
            #pragma unroll
            for (int r = 0; r < 4; ++r)
                hxn_s[aq*4 + r][CT*16 + am] = f2bf(fast_tanh(acc[r]));
        }
        __syncthreads();   // S1
        do_publish();

        // ---- ponder consume/compute loop (pk consumes step pk-1's output) ----
        for (int pk = 1; ; ++pk) {
            // spin: all 4 waves independently; own flag also orders wave0's hxn_s reads
            {
                const int pi = lane % 12;
                unsigned v;
                do { v = __hip_atomic_load(&flags[rg*16 + pi], __ATOMIC_RELAXED, ASCOPE); }
                while (!__all((int)(v >= it)));
            }
            __builtin_amdgcn_fence(__ATOMIC_ACQUIRE, "agent");
            const unsigned parR = (it - 1u) & 1u;
            const s16x8* exr = hxe + (size_t)(rg*2 + parR) * (NCH*64);
            const float* zpr = zpt + (size_t)(rg*2 + parR) * (RPG*CB);

            // z loads first (row am: 12 contiguous floats, 16B aligned)
            const float4* zb4 = (const float4*)(zpr + am*CB);
            const float4 z0 = zb4[0], z1 = zb4[1], z2 = zb4[2];
            // full new-hx A-frags (same data for all 4 waves; coalesced 16B loads)
            AU aload[NCH];
            #pragma unroll
            for (int ch = 0; ch < NCH; ++ch)
                aload[ch].f = *(const float4*)&exr[ch*64 + lane];

            // sigmoid + replicated scalar update (identical in all lanes/blocks)
            const float z = ((z0.x+z0.y)+(z0.z+z0.w))
                          + ((z1.x+z1.y)+(z1.z+z1.w))
                          + ((z2.x+z2.y)+(z2.z+z2.w));
            const float h = 1.f / (1.f + __expf(-(z + bp0)));
            float w1 = 0.f;
            if (act) {
                spc = -ah;
                ah += h;
                w1 = 1.f + (h - fmaxf(ah - 1.f, 0.f));   // 1 + p
                sc += 1.f;
                act = (ah < 0.99f) ? 1 : 0;               // 1-EPS == 0.99f exactly
            }
            const bool done = __all(act == 0) || (pk == MAXP);

            if (done) {
                // accumulate own slots (chunk ch owned iff (ch&3)==CT; ch const after unroll)
                #pragma unroll
                for (int ch = 0; ch < NCH; ++ch)
                    if ((ch & 3) == CT) {
                        const int j = ch >> 2;
                        #pragma unroll
                        for (int i = 0; i < 8; ++i)
                            ahx[j*8 + i] += w1 * bf2f(aload[ch].e[i]);
                    }
                break;
            }

            // matvec step pk: MFMA directly from loaded frags (no selection needed —
            // frozen rows' outputs are multiplied by w1=0 / gated by act downstream)
            f32x4 acc = xi;
            #pragma unroll
            for (int ch = 0; ch < NCH; ++ch)
                acc = __builtin_amdgcn_mfma_f32_16x16x32_bf16(
                        aload[ch].s, Breg[ch], acc, 0, 0, 0);
            // ahx accumulation hides under the MFMA chain (independent VALU)
            #pragma unroll
            for (int ch = 0; ch < NCH; ++ch)
                if ((ch & 3) == CT) {
                    const int j = ch >> 2;
                    #pragma unroll
                    for (int i = 0; i < 8; ++i)
                        ahx[j*8 + i] += w1 * bf2f(aload[ch].e[i]);
                }
            #pragma unroll
            for (int r = 0; r < 4; ++r)
                hxn_s[aq*4 + r][CT*16 + am] = f2bf(fast_tanh(acc[r] + wfl));
            __syncthreads();   // S1
            do_publish();
        }

        // ---- finalize t: hx_out = accum_hx / sc (all per-lane; barrier-free) ----
        const float inv = 1.f / sc;
        pc += spc;
        if (cbk == 0 && tid < RPG) out[OFF_STEPS + (size_t)t*BB + r0 + tid] = sc;
        #pragma unroll
        for (int j = 0; j < 6; ++j) {
            const int ch = j*4 + CT;
            float o[8];
            #pragma unroll
            for (int i = 0; i < 8; ++i) o[i] = ahx[j*8 + i] * inv;
            union { s16x8 v; unsigned short e[8]; } u;
            #pragma unroll
            for (int i = 0; i < 8; ++i) u.e[i] = f2bf(o[i]);
            A_s[ch*64 + lane] = u.v;   // next t's hx(k=0); guarded by next T0 barrier
            if (cbk == 0) {
                float* op = out + ((size_t)t*BB + r0 + am)*HH + ch*32 + aq*8;
                *(float4*)op       = make_float4(o[0], o[1], o[2], o[3]);
                *(float4*)(op + 4) = make_float4(o[4], o[5], o[6], o[7]);
                if (t == TT-1) {
                    float* lp = out + OFF_LAST + (size_t)(r0 + am)*HH + ch*32 + aq*8;
                    *(float4*)lp       = make_float4(o[0], o[1], o[2], o[3]);
                    *(float4*)(lp + 4) = make_float4(o[4], o[5], o[6], o[7]);
                }
            }
        }
    }
    if (cbk == 0 && tid < RPG) out[OFF_PCOST + r0 + tid] = pc;
}

extern "C" void kernel_launch(void* const* d_in, const int* in_sizes, int n_in,
                              void* d_out, int out_size, void* d_ws, size_t ws_size,
                              hipStream_t stream) {
    const float* x   = (const float*)d_in[0];
    const float* Wih = (const float*)d_in[1];
    const float* Whh = (const float*)d_in[2];
    const float* bih = (const float*)d_in[3];
    const float* bhh = (const float*)d_in[4];
    const float* wpv = (const float*)d_in[5];
    const float* bp  = (const float*)d_in[6];
    float* out = (float*)d_out;

    // ws: [0,4096) flags (zeroed); [4096,+393216) hx exchange (bf16 A-frag,
    // double-parity per rowgroup); then z partials (6144 B)
    unsigned* flags = (unsigned*)d_ws;
    s16x8*    hxe   = (s16x8*)((char*)d_ws + 4096);
    float*    zpt   = (float*)((char*)d_ws + 4096 + (size_t)RG*2*NCH*64*16);

    hipMemsetAsync(d_ws, 0, 4096, stream);
    act_kernel<<<dim3(RG*CB), dim3(NTH), 0, stream>>>(
        x, Wih, Whh, bih, bhh, wpv, bp, out, flags, hxe, zpt);
}

// Round 2
// 430.994 us; speedup vs baseline: 1.4492x; 1.4492x over previous
//
#include <hip/hip_runtime.h>
#include <math.h>

// Problem constants
#define TT 32
#define BB 128
#define DD 256
#define HH 768
#define MAXP 8

// Decomposition: 8 rowgroups (16 rows) x 12 col-blocks (64 cols), 256 thr (4 waves = 4 col-tiles)
#define RG   8
#define RPG  16
#define CB   12
#define CS   64
#define NTH  256
#define NCH  24    // K chunks of 32

#define OFF_LAST  ((size_t)TT * BB * HH)
#define OFF_PCOST (OFF_LAST + (size_t)BB * HH)
#define OFF_STEPS (OFF_PCOST + BB)

#define ASCOPE __HIP_MEMORY_SCOPE_AGENT

typedef __attribute__((ext_vector_type(8))) short s16x8;
typedef __attribute__((ext_vector_type(4))) float f32x4;
typedef unsigned long long ull;

static __device__ __forceinline__ unsigned short f2bf(float f) {
    unsigned u = __float_as_uint(f);
    u = (u + 0x7fffu + ((u >> 16) & 1u)) >> 16;   // RNE
    return (unsigned short)u;
}
static __device__ __forceinline__ float bf2f(unsigned short h) {
    return __uint_as_float(((unsigned)h) << 16);
}
// bf16-target precision is 2^-9; __expf error ~1e-6 is invisible. Handles +-inf limits.
static __device__ __forceinline__ float fast_tanh(float v) {
    return 1.f - 2.f / (__expf(2.f * v) + 1.f);
}

union AU { float4 f; s16x8 s; unsigned short e[8]; };

__launch_bounds__(NTH, 1)
__global__ void act_kernel(const float* __restrict__ x,
                           const float* __restrict__ Wih,
                           const float* __restrict__ Whh,
                           const float* __restrict__ bih,
                           const float* __restrict__ bhh,
                           const float* __restrict__ wpv,
                           const float* __restrict__ bp,
                           float* __restrict__ out,
                           unsigned* __restrict__ flags,
                           s16x8* __restrict__ hxe,
                           float* __restrict__ zpt)
{
    const int tid  = threadIdx.x;
    const int rg   = blockIdx.x & 7;     // rowgroup -> XCD (perf heuristic only)
    const int cbk  = blockIdx.x >> 3;    // col-block [0,12)
    const int r0   = rg * RPG;
    const int c0   = cbk * CS;
    const int CT   = tid >> 6;           // wave = col-tile [0,4)
    const int lane = tid & 63;
    const int am   = lane & 15;          // A-frag row / C-frag col
    const int aq   = lane >> 4;

    // LDS ~68 KB
    __shared__ s16x8 A_s[NCH * 64];        // hx(t, k=0) A-frags (written at finalize)
    __shared__ s16x8 WB_s[4 * 8 * 64];     // Wih B-frags (32 KB)
    __shared__ s16x8 xA_s[8 * 64];         // x_t A-frags (8 KB)
    __shared__ unsigned short hxn_s[RPG][72];   // new hx slice, bf16 (pad 72)
    __shared__ float wp_s[CS];

    // ---- init: Whh B-frags -> permanent VGPRs (96) ----
    s16x8 Breg[NCH];
    {
        const float* wr = Whh + (size_t)(c0 + CT*16 + am) * HH + aq*8;
        for (int ch = 0; ch < NCH; ++ch) {
            float4 a0 = *(const float4*)(wr + ch*32);
            float4 a1 = *(const float4*)(wr + ch*32 + 4);
            union { s16x8 v; unsigned short e[8]; } u;
            u.e[0]=f2bf(a0.x); u.e[1]=f2bf(a0.y); u.e[2]=f2bf(a0.z); u.e[3]=f2bf(a0.w);
            u.e[4]=f2bf(a1.x); u.e[5]=f2bf(a1.y); u.e[6]=f2bf(a1.z); u.e[7]=f2bf(a1.w);
            Breg[ch] = u.v;
        }
    }
    // Wih B-frags -> LDS (row stride 257 unaligned: scalar loads, init-only)
    for (int ch = 0; ch < 8; ++ch) {
        const float* wr = Wih + (size_t)(c0 + CT*16 + am) * (DD+1) + ch*32 + aq*8;
        union { s16x8 v; unsigned short e[8]; } u;
        #pragma unroll
        for (int j = 0; j < 8; ++j) u.e[j] = f2bf(wr[j]);
        WB_s[(CT*8 + ch)*64 + lane] = u.v;
    }
    if (tid < CS) wp_s[tid] = wpv[c0 + tid];
    // per-lane column constants (col = c0 + CT*16 + am)
    const int myc = c0 + CT*16 + am;
    const float bs_lane = bih[myc] + bhh[myc];
    const float wfl     = Wih[(size_t)myc*(DD+1) + DD];   // ponder-flag column
    const float bp0     = bp[0];
    {
        s16x8 z8 = {0,0,0,0,0,0,0,0};
        #pragma unroll
        for (int j = 0; j < 6; ++j) A_s[j*NTH + tid] = z8;   // hx0 = 0
    }

    float pc = 0.f;     // per-lane pcost for row am
    unsigned it = 0;    // monotone publish counter

    for (int t = 0; t < TT; ++t) {
        // ---- stage x_t slice as bf16 A-frags ----
        #pragma unroll
        for (int j = 0; j < 2; ++j) {
            const int s = j*NTH + tid;       // ch = s>>6, lane = s&63 == lane
            const int ch = s >> 6;
            const float* xb = x + ((size_t)t*BB + r0 + am)*DD + ch*32 + aq*8;
            float4 a0 = *(const float4*)xb;
            float4 a1 = *(const float4*)(xb + 4);
            union { s16x8 v; unsigned short e[8]; } u;
            u.e[0]=f2bf(a0.x); u.e[1]=f2bf(a0.y); u.e[2]=f2bf(a0.z); u.e[3]=f2bf(a0.w);
            u.e[4]=f2bf(a1.x); u.e[5]=f2bf(a1.y); u.e[6]=f2bf(a1.z); u.e[7]=f2bf(a1.w);
            xA_s[s] = u.v;
        }
        __syncthreads();   // T0: guards A_s (init/finalize) + xA_s writes

        // ---- xi tile per wave: x @ Wih^T + bias (MFMA, registers) ----
        f32x4 xi;
        {
            f32x4 a = {0.f,0.f,0.f,0.f};
            #pragma unroll
            for (int ch = 0; ch < 8; ++ch)
                a = __builtin_amdgcn_mfma_f32_16x16x32_bf16(
                        xA_s[ch*64 + lane], WB_s[(CT*8 + ch)*64 + lane], a, 0, 0, 0);
            xi[0]=a[0]+bs_lane; xi[1]=a[1]+bs_lane; xi[2]=a[2]+bs_lane; xi[3]=a[3]+bs_lane;
        }

        // per-lane replicated row state (row = am; 16 replicas compute identically)
        float ahx[48];
        #pragma unroll
        for (int q = 0; q < 48; ++q) ahx[q] = 0.f;
        float ah = 0.f, sc = 0.f, spc = 0.f;
        int act = 1;

        // ---- k=0 matvec from LDS A_s (hx carried from finalize; flag col = 0) ----
        {
            f32x4 acc = xi;
            #pragma unroll
            for (int ch = 0; ch < NCH; ++ch)
                acc = __builtin_amdgcn_mfma_f32_16x16x32_bf16(
                        A_s[ch*64 + lane], Breg[ch], acc, 0, 0, 0);
            #pragma unroll
            for (int r = 0; r < 4; ++r)
                hxn_s[aq*4 + r][CT*16 + am] = f2bf(fast_tanh(acc[r]));
        }
        __syncthreads();   // S1: hxn_s ready for wave0 publish

        // ---- ponder exchange/consume loop (iteration pk consumes publish pk-1) ----
        for (int pk = 1; ; ++pk) {
            const unsigned par = it & 1u;

            // wave 0: publish + fence + flag + LONE spin + acquire.
            // Waves 1-3 are PARKED at S2 (quiescent — no vmem traffic while the
            // publisher drains its stores and the flag line propagates).
            if (CT == 0) {
                ull*   exw = (ull*)(hxe + (size_t)(rg*2 + par) * (NCH*64));
                float* zpw = zpt + (size_t)(rg*2 + par) * (RPG*CB);
                // hx slice (2 chunks, A-frag layout); write-through atomic stores so
                // visibility does not depend on workgroup->XCD mapping
                const ull* s0 = (const ull*)&hxn_s[am][aq*8];
                const ull* s1 = (const ull*)&hxn_s[am][32 + aq*8];
                ull* d0 = exw + ((size_t)(2*cbk)*64   + lane)*2;
                ull* d1 = exw + ((size_t)(2*cbk+1)*64 + lane)*2;
                __hip_atomic_store(d0,   s0[0], __ATOMIC_RELAXED, ASCOPE);
                __hip_atomic_store(d0+1, s0[1], __ATOMIC_RELAXED, ASCOPE);
                __hip_atomic_store(d1,   s1[0], __ATOMIC_RELAXED, ASCOPE);
                __hip_atomic_store(d1+1, s1[1], __ATOMIC_RELAXED, ASCOPE);
                // z partials: lane -> (row zr, 16-col group zc); pair-tree over zc
                const int zr = lane >> 2, zc = lane & 3;
                float sz = 0.f;
                #pragma unroll
                for (int i = 0; i < 16; ++i)
                    sz += bf2f(hxn_s[zr][zc*16 + i]) * wp_s[zc*16 + i];
                sz += __shfl_xor(sz, 1);
                sz += __shfl_xor(sz, 2);
                if (zc == 0)
                    __hip_atomic_store(&zpw[zr*CB + cbk], sz, __ATOMIC_RELAXED, ASCOPE);
                __builtin_amdgcn_fence(__ATOMIC_RELEASE, "agent");
                if (lane == 0)
                    __hip_atomic_store(&flags[rg*16 + cbk], it + 1u, __ATOMIC_RELAXED, ASCOPE);
                // lone spin for all 12 col-blocks of this rowgroup
                const int pi = lane % 12;
                unsigned v;
                do { v = __hip_atomic_load(&flags[rg*16 + pi], __ATOMIC_RELAXED, ASCOPE); }
                while (!__all((int)(v >= it + 1u)));
                // one cache-invalidate per block per round; also covers waves 1-3's
                // plain loads after S2 (same CU -> same L1/L2)
                __builtin_amdgcn_fence(__ATOMIC_ACQUIRE, "agent");
            }
            ++it;
            __syncthreads();   // S2: data visible; waves 1-3 resume

            const s16x8* exr = hxe + (size_t)(rg*2 + par) * (NCH*64);
            const float* zpr = zpt + (size_t)(rg*2 + par) * (RPG*CB);

            // z loads first (row am: 12 contiguous floats, 16B aligned)
            const float4* zb4 = (const float4*)(zpr + am*CB);
            const float4 z0 = zb4[0], z1 = zb4[1], z2 = zb4[2];
            // full new-hx A-frags; wave0 fills L1, waves 1-3 mostly hit it
            AU aload[NCH];
            #pragma unroll
            for (int ch = 0; ch < NCH; ++ch)
                aload[ch].f = *(const float4*)&exr[ch*64 + lane];

            // sigmoid + replicated scalar update (identical in all lanes/blocks)
            const float z = ((z0.x+z0.y)+(z0.z+z0.w))
                          + ((z1.x+z1.y)+(z1.z+z1.w))
                          + ((z2.x+z2.y)+(z2.z+z2.w));
            const float h = 1.f / (1.f + __expf(-(z + bp0)));
            float w1 = 0.f;
            if (act) {
                spc = -ah;
                ah += h;
                w1 = 1.f + (h - fmaxf(ah - 1.f, 0.f));   // 1 + p
                sc += 1.f;
                act = (ah < 0.99f) ? 1 : 0;               // 1-EPS == 0.99f exactly
            }
            const bool done = __all(act == 0) || (pk == MAXP);

            if (done) {
                // accumulate own slots (chunk ch owned iff (ch&3)==CT)
                #pragma unroll
                for (int ch = 0; ch < NCH; ++ch)
                    if ((ch & 3) == CT) {
                        const int j = ch >> 2;
                        #pragma unroll
                        for (int i = 0; i < 8; ++i)
                            ahx[j*8 + i] += w1 * bf2f(aload[ch].e[i]);
                    }
                break;
            }

            // matvec step pk: MFMA directly from loaded frags (no selection needed —
            // frozen rows' outputs are multiplied by w1=0 / gated by act downstream)
            f32x4 acc = xi;
            #pragma unroll
            for (int ch = 0; ch < NCH; ++ch)
                acc = __builtin_amdgcn_mfma_f32_16x16x32_bf16(
                        aload[ch].s, Breg[ch], acc, 0, 0, 0);
            // ahx accumulation hides under the MFMA chain (independent VALU)
            #pragma unroll
            for (int ch = 0; ch < NCH; ++ch)
                if ((ch & 3) == CT) {
                    const int j = ch >> 2;
                    #pragma unroll
                    for (int i = 0; i < 8; ++i)
                        ahx[j*8 + i] += w1 * bf2f(aload[ch].e[i]);
                }
            #pragma unroll
            for (int r = 0; r < 4; ++r)
                hxn_s[aq*4 + r][CT*16 + am] = f2bf(fast_tanh(acc[r] + wfl));
            __syncthreads();   // S1: hxn_s ready for next publish
        }

        // ---- finalize t: hx_out = accum_hx / sc (all per-lane; barrier-free) ----
        const float inv = 1.f / sc;
        pc += spc;
        if (cbk == 0 && tid < RPG) out[OFF_STEPS + (size_t)t*BB + r0 + tid] = sc;
        #pragma unroll
        for (int j = 0; j < 6; ++j) {
            const int ch = j*4 + CT;
            float o[8];
            #pragma unroll
            for (int i = 0; i < 8; ++i) o[i] = ahx[j*8 + i] * inv;
            union { s16x8 v; unsigned short e[8]; } u;
            #pragma unroll
            for (int i = 0; i < 8; ++i) u.e[i] = f2bf(o[i]);
            A_s[ch*64 + lane] = u.v;   // next t's hx(k=0); guarded by next T0 barrier
            if (cbk == 0) {
                float* op = out + ((size_t)t*BB + r0 + am)*HH + ch*32 + aq*8;
                *(float4*)op       = make_float4(o[0], o[1], o[2], o[3]);
                *(float4*)(op + 4) = make_float4(o[4], o[5], o[6], o[7]);
                if (t == TT-1) {
                    float* lp = out + OFF_LAST + (size_t)(r0 + am)*HH + ch*32 + aq*8;
                    *(float4*)lp       = make_float4(o[0], o[1], o[2], o[3]);
                    *(float4*)(lp + 4) = make_float4(o[4], o[5], o[6], o[7]);
                }
            }
        }
    }
    if (cbk == 0 && tid < RPG) out[OFF_PCOST + r0 + tid] = pc;
}

extern "C" void kernel_launch(void* const* d_in, const int* in_sizes, int n_in,
                              void* d_out, int out_size, void* d_ws, size_t ws_size,
                              hipStream_t stream) {
    const float* x   = (const float*)d_in[0];
    const float* Wih = (const float*)d_in[1];
    const float* Whh = (const float*)d_in[2];
    const float* bih = (const float*)d_in[3];
    const float* bhh = (const float*)d_in[4];
    const float* wpv = (const float*)d_in[5];
    const float* bp  = (const float*)d_in[6];
    float* out = (float*)d_out;

    // ws: [0,4096) flags (zeroed); [4096,+393216) hx exchange (bf16 A-frag,
    // double-parity per rowgroup); then z partials (6144 B)
    unsigned* flags = (unsigned*)d_ws;
    s16x8*    hxe   = (s16x8*)((char*)d_ws + 4096);
    float*    zpt   = (float*)((char*)d_ws + 4096 + (size_t)RG*2*NCH*64*16);

    hipMemsetAsync(d_ws, 0, 4096, stream);
    act_kernel<<<dim3(RG*CB), dim3(NTH), 0, stream>>>(
        x, Wih, Whh, bih, bhh, wpv, bp, out, flags, hxe, zpt);
}

// Round 3
// 352.368 us; speedup vs baseline: 1.7725x; 1.2231x over previous
//
#include <hip/hip_runtime.h>
#include <math.h>

// Problem constants
#define TT 32
#define BB 128
#define DD 256
#define HH 768
#define MAXP 8

// Decomposition: 8 rowgroups (16 rows) x 12 col-blocks (64 cols), 256 thr (4 waves = 4 col-tiles)
#define RG   8
#define RPG  16
#define CB   12
#define CS   64
#define NTH  256
#define NCH  24    // K chunks of 32

#define OFF_LAST  ((size_t)TT * BB * HH)
#define OFF_PCOST (OFF_LAST + (size_t)BB * HH)
#define OFF_STEPS (OFF_PCOST + BB)

#define ASCOPE __HIP_MEMORY_SCOPE_AGENT

typedef __attribute__((ext_vector_type(8))) short s16x8;
typedef __attribute__((ext_vector_type(4))) float f32x4;
typedef unsigned long long ull;

static __device__ __forceinline__ unsigned short f2bf(float f) {
    unsigned u = __float_as_uint(f);
    u = (u + 0x7fffu + ((u >> 16) & 1u)) >> 16;   // RNE
    return (unsigned short)u;
}
static __device__ __forceinline__ float bf2f(unsigned short h) {
    return __uint_as_float(((unsigned)h) << 16);
}
// bf16-target precision is 2^-9; __expf error ~1e-6 is invisible. Handles +-inf limits.
static __device__ __forceinline__ float fast_tanh(float v) {
    return 1.f - 2.f / (__expf(2.f * v) + 1.f);
}

__launch_bounds__(NTH, 1)
__global__ void act_kernel(const float* __restrict__ x,
                           const float* __restrict__ Wih,
                           const float* __restrict__ Whh,
                           const float* __restrict__ bih,
                           const float* __restrict__ bhh,
                           const float* __restrict__ wpv,
                           const float* __restrict__ bp,
                           float* __restrict__ out,
                           unsigned* __restrict__ flags,
                           s16x8* __restrict__ hxe,
                           float* __restrict__ zpt)
{
    const int tid  = threadIdx.x;
    const int rg   = blockIdx.x & 7;     // rowgroup -> XCD (perf heuristic only)
    const int cbk  = blockIdx.x >> 3;    // col-block [0,12)
    const int r0   = rg * RPG;
    const int c0   = cbk * CS;
    const int CT   = tid >> 6;           // wave = col-tile [0,4)
    const int lane = tid & 63;
    const int am   = lane & 15;          // A-frag row / C-frag col
    const int aq   = lane >> 4;

    // LDS ~68 KB
    __shared__ s16x8 A_s[NCH * 64];        // current hx A-frags (finalize or exchange)
    __shared__ s16x8 WB_s[4 * 8 * 64];     // Wih B-frags (32 KB)
    __shared__ s16x8 xA_s[8 * 64];         // x_t A-frags (8 KB)
    __shared__ unsigned short hxn_s[RPG][72];   // new hx slice, bf16 (pad 72)
    __shared__ float wp_s[CS];

    // ---- init: Whh B-frags -> permanent VGPRs (96) ----
    s16x8 Breg[NCH];
    {
        const float* wr = Whh + (size_t)(c0 + CT*16 + am) * HH + aq*8;
        for (int ch = 0; ch < NCH; ++ch) {
            float4 a0 = *(const float4*)(wr + ch*32);
            float4 a1 = *(const float4*)(wr + ch*32 + 4);
            union { s16x8 v; unsigned short e[8]; } u;
            u.e[0]=f2bf(a0.x); u.e[1]=f2bf(a0.y); u.e[2]=f2bf(a0.z); u.e[3]=f2bf(a0.w);
            u.e[4]=f2bf(a1.x); u.e[5]=f2bf(a1.y); u.e[6]=f2bf(a1.z); u.e[7]=f2bf(a1.w);
            Breg[ch] = u.v;
        }
    }
    // Wih B-frags -> LDS (row stride 257 unaligned: scalar loads, init-only)
    for (int ch = 0; ch < 8; ++ch) {
        const float* wr = Wih + (size_t)(c0 + CT*16 + am) * (DD+1) + ch*32 + aq*8;
        union { s16x8 v; unsigned short e[8]; } u;
        #pragma unroll
        for (int j = 0; j < 8; ++j) u.e[j] = f2bf(wr[j]);
        WB_s[(CT*8 + ch)*64 + lane] = u.v;
    }
    if (tid < CS) wp_s[tid] = wpv[c0 + tid];
    // per-lane column constants (col = c0 + CT*16 + am)
    const int myc = c0 + CT*16 + am;
    const float bs_lane = bih[myc] + bhh[myc];
    const float wfl     = Wih[(size_t)myc*(DD+1) + DD];   // ponder-flag column
    const float bp0     = bp[0];
    {
        s16x8 z8 = {0,0,0,0,0,0,0,0};
        #pragma unroll
        for (int j = 0; j < 6; ++j) A_s[j*NTH + tid] = z8;   // hx0 = 0
    }

    float pc = 0.f;     // per-lane pcost for row am
    unsigned it = 0;    // number of publishes completed by this block

    // Publish: wave 0 pushes hxn_s (A-frag layout) + 16 z-row partials via agent-scope
    // write-through atomic stores, waits for its OWN stores to reach the coherence
    // point (raw vmcnt(0) -- no L2-flushing fence), then sets the flag.
    auto publish = [&]() {
        const unsigned par = it & 1u;
        if (CT == 0) {
            ull*   exw = (ull*)(hxe + (size_t)(rg*2 + par) * (NCH*64));
            float* zpw = zpt + (size_t)(rg*2 + par) * (RPG*CB);
            const ull* s0 = (const ull*)&hxn_s[am][aq*8];
            const ull* s1 = (const ull*)&hxn_s[am][32 + aq*8];
            ull* d0 = exw + ((size_t)(2*cbk)*64   + lane)*2;
            ull* d1 = exw + ((size_t)(2*cbk+1)*64 + lane)*2;
            __hip_atomic_store(d0,   s0[0], __ATOMIC_RELAXED, ASCOPE);
            __hip_atomic_store(d0+1, s0[1], __ATOMIC_RELAXED, ASCOPE);
            __hip_atomic_store(d1,   s1[0], __ATOMIC_RELAXED, ASCOPE);
            __hip_atomic_store(d1+1, s1[1], __ATOMIC_RELAXED, ASCOPE);
            // z partials: lane -> (row zr, 16-col group zc); pair-tree over zc
            const int zr = lane >> 2, zc = lane & 3;
            float sz = 0.f;
            #pragma unroll
            for (int i = 0; i < 16; ++i)
                sz += bf2f(hxn_s[zr][zc*16 + i]) * wp_s[zc*16 + i];
            sz += __shfl_xor(sz, 1);
            sz += __shfl_xor(sz, 2);
            if (zc == 0)
                __hip_atomic_store(&zpw[zr*CB + cbk], sz, __ATOMIC_RELAXED, ASCOPE);
            // completion-ack of all prior vmem stores, THEN flag issue => happens-before
            asm volatile("s_waitcnt vmcnt(0)" ::: "memory");
            if (lane == 0)
                __hip_atomic_store(&flags[rg*16 + cbk], it + 1u, __ATOMIC_RELAXED, ASCOPE);
        }
        ++it;
    };

    for (int t = 0; t < TT; ++t) {
        // ---- stage x_t slice as bf16 A-frags ----
        #pragma unroll
        for (int j = 0; j < 2; ++j) {
            const int s = j*NTH + tid;       // ch = s>>6, slot lane = lane
            const int ch = s >> 6;
            const float* xb = x + ((size_t)t*BB + r0 + am)*DD + ch*32 + aq*8;
            float4 a0 = *(const float4*)xb;
            float4 a1 = *(const float4*)(xb + 4);
            union { s16x8 v; unsigned short e[8]; } u;
            u.e[0]=f2bf(a0.x); u.e[1]=f2bf(a0.y); u.e[2]=f2bf(a0.z); u.e[3]=f2bf(a0.w);
            u.e[4]=f2bf(a1.x); u.e[5]=f2bf(a1.y); u.e[6]=f2bf(a1.z); u.e[7]=f2bf(a1.w);
            xA_s[s] = u.v;
        }
        __syncthreads();   // T0: guards A_s (init/finalize) + xA_s writes

        // ---- xi tile per wave: x @ Wih^T + bias (MFMA, registers) ----
        f32x4 xi;
        {
            f32x4 a = {0.f,0.f,0.f,0.f};
            #pragma unroll
            for (int ch = 0; ch < 8; ++ch)
                a = __builtin_amdgcn_mfma_f32_16x16x32_bf16(
                        xA_s[ch*64 + lane], WB_s[(CT*8 + ch)*64 + lane], a, 0, 0, 0);
            xi[0]=a[0]+bs_lane; xi[1]=a[1]+bs_lane; xi[2]=a[2]+bs_lane; xi[3]=a[3]+bs_lane;
        }

        // per-lane replicated row state (row = am; 16 replicas compute identically)
        float ahx[48];
        #pragma unroll
        for (int q = 0; q < 48; ++q) ahx[q] = 0.f;
        float ah = 0.f, sc = 0.f, spc = 0.f;
        int act = 1;

        // ---- k=0 matvec from LDS A_s (hx carried from finalize; flag col = 0) ----
        {
            f32x4 acc = xi;
            #pragma unroll
            for (int ch = 0; ch < NCH; ++ch)
                acc = __builtin_amdgcn_mfma_f32_16x16x32_bf16(
                        A_s[ch*64 + lane], Breg[ch], acc, 0, 0, 0);
            #pragma unroll
            for (int r = 0; r < 4; ++r)
                hxn_s[aq*4 + r][CT*16 + am] = f2bf(fast_tanh(acc[r]));
        }
        __syncthreads();   // S1: hxn_s ready for wave0 publish
        publish();

        // ---- ponder exchange/consume loop (iteration pk consumes publish pk) ----
        for (int pk = 1; ; ++pk) {
            // lone spinner; waves 1-3 parked at S2 (no vmem traffic during exchange)
            if (CT == 0) {
                const int pi = lane % 12;
                unsigned v;
                do { v = __hip_atomic_load(&flags[rg*16 + pi], __ATOMIC_RELAXED, ASCOPE); }
                while (!__all((int)(v >= it)));
            }
            __syncthreads();   // S2

            const unsigned parR = (it - 1u) & 1u;
            const ull*   exr = (const ull*)(hxe + (size_t)(rg*2 + parR) * (NCH*64));
            const float* zpr = zpt + (size_t)(rg*2 + parR) * (RPG*CB);

            // cooperative consume: each thread owns 6 chunks (ch = j*4+CT, slot = lane).
            // ALL cross-block reads are agent-scope atomics (coherent; no acquire fence,
            // no L1/L2 invalidate => x/Wih/out stay cached).
            ull clo[6], chi[6];
            #pragma unroll
            for (int j = 0; j < 6; ++j) {
                const ull* src = exr + ((size_t)((j*4 + CT)*64 + lane))*2;
                clo[j] = __hip_atomic_load(src,     __ATOMIC_RELAXED, ASCOPE);
                chi[j] = __hip_atomic_load(src + 1, __ATOMIC_RELAXED, ASCOPE);
            }
            // z partials for row am: 12 floats = 6 x 8B atomic loads
            ull zu[6];
            {
                const ull* zb = (const ull*)(zpr + am*CB);
                #pragma unroll
                for (int j = 0; j < 6; ++j)
                    zu[j] = __hip_atomic_load(zb + j, __ATOMIC_RELAXED, ASCOPE);
            }
            // redistribute own chunks into LDS A-frags (z math hides under this drain)
            #pragma unroll
            for (int j = 0; j < 6; ++j) {
                union { ull u[2]; s16x8 v; } cv;
                cv.u[0] = clo[j]; cv.u[1] = chi[j];
                A_s[(j*4 + CT)*64 + lane] = cv.v;
            }

            // z sum -- same association tree as before: ((0..3)+(4..7))+(8..11)
            float zf[12];
            #pragma unroll
            for (int j = 0; j < 6; ++j) {
                zf[2*j]   = __uint_as_float((unsigned)(zu[j] & 0xffffffffu));
                zf[2*j+1] = __uint_as_float((unsigned)(zu[j] >> 32));
            }
            const float zA = (zf[0]+zf[1]) + (zf[2]+zf[3]);
            const float zB = (zf[4]+zf[5]) + (zf[6]+zf[7]);
            const float zC = (zf[8]+zf[9]) + (zf[10]+zf[11]);
            const float z  = (zA + zB) + zC;
            const float h  = 1.f / (1.f + __expf(-(z + bp0)));
            float w1 = 0.f;
            if (act) {
                spc = -ah;
                ah += h;
                w1 = 1.f + (h - fmaxf(ah - 1.f, 0.f));   // 1 + p
                sc += 1.f;
                act = (ah < 0.99f) ? 1 : 0;               // 1-EPS == 0.99f exactly
            }
            const bool done = __all(act == 0) || (pk == MAXP);   // block-uniform

            if (done) {
                #pragma unroll
                for (int j = 0; j < 6; ++j) {
                    #pragma unroll
                    for (int i = 0; i < 4; ++i) {
                        ahx[j*8 + i]     += w1 * bf2f((unsigned short)(clo[j] >> (16*i)));
                        ahx[j*8 + 4 + i] += w1 * bf2f((unsigned short)(chi[j] >> (16*i)));
                    }
                }
                break;
            }
            __syncthreads();   // S3: A_s fully redistributed

            // matvec step pk: MFMA from LDS (frozen rows' outputs are w1=0-gated)
            f32x4 acc = xi;
            #pragma unroll
            for (int ch = 0; ch < NCH; ++ch)
                acc = __builtin_amdgcn_mfma_f32_16x16x32_bf16(
                        A_s[ch*64 + lane], Breg[ch], acc, 0, 0, 0);
            // ahx accumulation (independent VALU, hides under the MFMA chain)
            #pragma unroll
            for (int j = 0; j < 6; ++j) {
                #pragma unroll
                for (int i = 0; i < 4; ++i) {
                    ahx[j*8 + i]     += w1 * bf2f((unsigned short)(clo[j] >> (16*i)));
                    ahx[j*8 + 4 + i] += w1 * bf2f((unsigned short)(chi[j] >> (16*i)));
                }
            }
            #pragma unroll
            for (int r = 0; r < 4; ++r)
                hxn_s[aq*4 + r][CT*16 + am] = f2bf(fast_tanh(acc[r] + wfl));
            __syncthreads();   // S1: hxn_s ready for next publish
            publish();
        }

        // ---- finalize t: hx_out = accum_hx / sc (all per-lane; barrier-free) ----
        const float inv = 1.f / sc;
        pc += spc;
        if (cbk == 0 && tid < RPG) out[OFF_STEPS + (size_t)t*BB + r0 + tid] = sc;
        #pragma unroll
        for (int j = 0; j < 6; ++j) {
            const int ch = j*4 + CT;
            float o[8];
            #pragma unroll
            for (int i = 0; i < 8; ++i) o[i] = ahx[j*8 + i] * inv;
            union { s16x8 v; unsigned short e[8]; } u;
            #pragma unroll
            for (int i = 0; i < 8; ++i) u.e[i] = f2bf(o[i]);
            A_s[ch*64 + lane] = u.v;   // next t's hx(k=0); guarded by next T0 barrier
            if (cbk == 0) {
                float* op = out + ((size_t)t*BB + r0 + am)*HH + ch*32 + aq*8;
                *(float4*)op       = make_float4(o[0], o[1], o[2], o[3]);
                *(float4*)(op + 4) = make_float4(o[4], o[5], o[6], o[7]);
                if (t == TT-1) {
                    float* lp = out + OFF_LAST + (size_t)(r0 + am)*HH + ch*32 + aq*8;
                    *(float4*)lp       = make_float4(o[0], o[1], o[2], o[3]);
                    *(float4*)(lp + 4) = make_float4(o[4], o[5], o[6], o[7]);
                }
            }
        }
    }
    if (cbk == 0 && tid < RPG) out[OFF_PCOST + r0 + tid] = pc;
}

extern "C" void kernel_launch(void* const* d_in, const int* in_sizes, int n_in,
                              void* d_out, int out_size, void* d_ws, size_t ws_size,
                              hipStream_t stream) {
    const float* x   = (const float*)d_in[0];
    const float* Wih = (const float*)d_in[1];
    const float* Whh = (const float*)d_in[2];
    const float* bih = (const float*)d_in[3];
    const float* bhh = (const float*)d_in[4];
    const float* wpv = (const float*)d_in[5];
    const float* bp  = (const float*)d_in[6];
    float* out = (float*)d_out;

    // ws: [0,4096) flags (zeroed); [4096,+393216) hx exchange (bf16 A-frag,
    // double-parity per rowgroup); then z partials (6144 B)
    unsigned* flags = (unsigned*)d_ws;
    s16x8*    hxe   = (s16x8*)((char*)d_ws + 4096);
    float*    zpt   = (float*)((char*)d_ws + 4096 + (size_t)RG*2*NCH*64*16);

    hipMemsetAsync(d_ws, 0, 4096, stream);
    act_kernel<<<dim3(RG*CB), dim3(NTH), 0, stream>>>(
        x, Wih, Whh, bih, bhh, wpv, bp, out, flags, hxe, zpt);
}